// Round 2
// baseline (2538.395 us; speedup 1.0000x reference)
//
#include <hip/hip_runtime.h>
#include <math.h>

// clDice loss on MI355X (gfx950).
// pred, gt: (16,1,1024,1024) fp32. soft_skeletonize = 20 iterations of
//   min = minpool3(x); contour = relu(maxpool3(min) - min); x = relu(x - contour)
// fused per-iteration into one kernel via LDS halo tiles. The two tensors are
// skeletonized SEQUENTIALLY through two 16-image ping-pong buffers so the
// workspace stays at 134 MB + 256 B (previous 268 MB + 32 B layout overflowed
// ws_size == 256 MiB by exactly the accumulator bytes -> device fault).

#define IMG_H 1024
#define IMG_W 1024
#define IMG_N (IMG_H * IMG_W)   // 1048576
#define NIMG  16                // images per tensor
#define TS    64                // output tile edge
#define SXW   (TS + 4)          // 68: x tile with halo 2
#define SMW   (TS + 2)          // 66: minpool tile with halo 1
#define ITERS 20

__global__ __launch_bounds__(256) void skel_iter(
    const float* __restrict__ src,    // 16-image source
    float* __restrict__ dst)          // 16-image destination
{
    __shared__ float sx[SXW * SXW];   // x with halo 2 (OOB = +inf)
    __shared__ float sm[SMW * SMW];   // minpool with halo 1 (OOB center = -inf)

    const int bx = blockIdx.x * TS, by = blockIdx.y * TS;
    const int t = threadIdx.x;
    const float* s = src + (size_t)blockIdx.z * IMG_N;

    // ---- load x tile with halo 2; out-of-image = +inf (min-pool identity) ----
    for (int idx = t; idx < SXW * SXW; idx += 256) {
        int ly = idx / SXW, lx = idx - ly * SXW;
        int gy = by + ly - 2, gx = bx + lx - 2;
        float v = INFINITY;
        if ((unsigned)gy < IMG_H && (unsigned)gx < IMG_W)
            v = s[gy * IMG_W + gx];
        sx[idx] = v;
    }
    __syncthreads();

    // ---- minpool3 into sm; centers outside image = -inf (max-pool padding) ----
    for (int idx = t; idx < SMW * SMW; idx += 256) {
        int my = idx / SMW, mx = idx - my * SMW;
        int gy = by + my - 1, gx = bx + mx - 1;
        float m = -INFINITY;
        if ((unsigned)gy < IMG_H && (unsigned)gx < IMG_W) {
            const float* p = &sx[my * SXW + mx];
            float a0 = fminf(fminf(p[0],           p[1]),             p[2]);
            float a1 = fminf(fminf(p[SXW],         p[SXW + 1]),       p[SXW + 2]);
            float a2 = fminf(fminf(p[2 * SXW],     p[2 * SXW + 1]),   p[2 * SXW + 2]);
            m = fminf(fminf(a0, a1), a2);
        }
        sm[idx] = m;
    }
    __syncthreads();

    // ---- maxpool3(minpool) -> contour -> relu(x - contour); 16 rows/thread ----
    float* out = dst + (size_t)blockIdx.z * IMG_N;
    const int ox = t & (TS - 1);
    const int ry = t >> 6;                      // 0..3
    for (int k = 0; k < TS / 4; ++k) {
        const int oy = ry + 4 * k;              // 0..63
        const float* p = &sm[oy * SMW + ox];
        float b0 = fmaxf(fmaxf(p[0],           p[1]),             p[2]);
        float b1 = fmaxf(fmaxf(p[SMW],         p[SMW + 1]),       p[SMW + 2]);
        float b2 = fmaxf(fmaxf(p[2 * SMW],     p[2 * SMW + 1]),   p[2 * SMW + 2]);
        float mv = fmaxf(fmaxf(b0, b1), b2);
        float minc = p[SMW + 1];                // minpool at center
        float contour = fmaxf(mv - minc, 0.0f);
        float x = sx[(oy + 2) * SXW + (ox + 2)];
        out[(size_t)(by + oy) * IMG_W + (bx + ox)] = fmaxf(x - contour, 0.0f);
    }
}

// acc2[0] += sum(skel * other); acc2[1] += sum(skel)
__global__ __launch_bounds__(256) void reduce2(
    const float* __restrict__ skel,
    const float* __restrict__ other,
    double* __restrict__ acc2)
{
    const size_t N = (size_t)NIMG * IMG_N;
    size_t i = (size_t)blockIdx.x * 256 + threadIdx.x;
    const size_t stride = (size_t)gridDim.x * 256;
    float s1 = 0.f, s2 = 0.f;
    for (; i < N; i += stride) {
        float sk = skel[i];
        s1 += sk * other[i];
        s2 += sk;
    }
    double d1 = s1, d2 = s2;
    for (int off = 32; off; off >>= 1) {
        d1 += __shfl_down(d1, off);
        d2 += __shfl_down(d2, off);
    }
    if ((threadIdx.x & 63) == 0) {
        atomicAdd(&acc2[0], d1);
        atomicAdd(&acc2[1], d2);
    }
}

__global__ void zero_acc(double* __restrict__ acc)
{
    if (threadIdx.x < 4) acc[threadIdx.x] = 0.0;
}

__global__ void finalize(const double* __restrict__ acc, float* __restrict__ out)
{
    double iflat = (acc[0] + 1.0) / (acc[1] + 1.0);
    double tflat = (acc[2] + 1.0) / (acc[3] + 1.0);
    double inter = iflat * tflat;
    out[0] = (float)(1.0 - 2.0 * inter / (iflat + tflat));
}

extern "C" void kernel_launch(void* const* d_in, const int* in_sizes, int n_in,
                              void* d_out, int out_size, void* d_ws, size_t ws_size,
                              hipStream_t stream)
{
    const float* pred = (const float*)d_in[0];
    const float* gt   = (const float*)d_in[1];

    double* acc  = (double*)d_ws;                              // 4 doubles @ +0
    float*  bufA = (float*)((char*)d_ws + 256);                // 16 images
    float*  bufB = bufA + (size_t)NIMG * IMG_N;                // 16 images
    // total ws use: 256 B + 134,217,728 B

    zero_acc<<<1, 64, 0, stream>>>(acc);

    dim3 grid(IMG_W / TS, IMG_H / TS, NIMG);

    // ---- skeletonize pred ----
    skel_iter<<<grid, 256, 0, stream>>>(pred, bufA);
    for (int i = 1; i < ITERS; ++i) {
        const float* sp = (i & 1) ? bufA : bufB;
        float*       dp = (i & 1) ? bufB : bufA;
        skel_iter<<<grid, 256, 0, stream>>>(sp, dp);
    }
    // ITERS=20 -> final skeleton in bufB
    reduce2<<<1024, 256, 0, stream>>>(bufB, gt, acc);          // iflat sums

    // ---- skeletonize gt ----
    skel_iter<<<grid, 256, 0, stream>>>(gt, bufA);
    for (int i = 1; i < ITERS; ++i) {
        const float* sp = (i & 1) ? bufA : bufB;
        float*       dp = (i & 1) ? bufB : bufA;
        skel_iter<<<grid, 256, 0, stream>>>(sp, dp);
    }
    reduce2<<<1024, 256, 0, stream>>>(bufB, pred, acc + 2);    // tflat sums

    finalize<<<1, 1, 0, stream>>>(acc, (float*)d_out);
}

// Round 3
// 2452.068 us; speedup vs baseline: 1.0352x; 1.0352x over previous
//
#include <hip/hip_runtime.h>
#include <math.h>

// clDice loss on MI355X (gfx950).
// soft_skeletonize = 20 iterations of:
//   m = minpool3(x); contour = relu(maxpool3(m) - m); x = relu(x - contour)
// Round-3 design: separable 3x3 min/max (h-min3, v-min3, h-max3, v-max3) with
// ALL LDS traffic as aligned float4 (ds_read/write_b128). Round-2 version was
// LDS-throughput-bound on scalar ds_read_b32 (~9-11 reads per element,
// ~8500 LDS cycles/block -> 56 us/launch). This cuts LDS work ~3.3x.
// x is read straight from global (VMEM pipe, L1/L2-resident) instead of an
// LDS stage, overlapping the two pipes.

#define IMG_H 1024
#define IMG_W 1024
#define IMG_N (IMG_H * IMG_W)
#define NIMG  16
#define TS    64
#define P     68      // LDS row pitch (floats); 272 B rows, 16B-aligned
#define ITERS 20

__global__ __launch_bounds__(256) void skel_iter(
    const float* __restrict__ src,
    float* __restrict__ dst)
{
    // shm: phase A = h-min3 rows y=by-2..by+65 (68 rows);
    //      phase C reuses it for h-max3 rows y=by-1..by+64 (66 rows)
    // sm : min-pool m, rows y=by-1..by+64 (66 rows); col s <-> x = bx+s-2
    __shared__ __align__(16) float shm[68 * P];
    __shared__ __align__(16) float sm [66 * P];

    const int bx = blockIdx.x * TS, by = blockIdx.y * TS;
    const int t = threadIdx.x;
    const float* s = src + (size_t)blockIdx.z * IMG_N;
    float*       o = dst + (size_t)blockIdx.z * IMG_N;
    const float INF = __builtin_huge_valf();

    // ---- Phase A: horizontal min3 of x -> shm ----
    // storage col sc in [0,67] <-> center x = bx + sc - 2
    for (int item = t; item < 68 * 17; item += 256) {
        int r = item / 17, q = item - r * 17;
        int y = by + r - 2;
        float4 A = make_float4(INF, INF, INF, INF);
        float4 B = A;
        if ((unsigned)y < (unsigned)IMG_H) {
            const float* rowp = s + (size_t)y * IMG_W;
            int colA = bx + 4 * q - 4;          // 16B-aligned
            int colB = bx + 4 * q;
            if (colA >= 0)    A = *(const float4*)(rowp + colA);
            if (colB < IMG_W) B = *(const float4*)(rowp + colB);
        }
        float w1 = A.y, w2 = A.z, w3 = A.w, w4 = B.x, w5 = B.y, w6 = B.z;
        float4 h;
        h.x = fminf(fminf(w1, w2), w3);
        h.y = fminf(fminf(w2, w3), w4);
        h.z = fminf(fminf(w3, w4), w5);
        h.w = fminf(fminf(w4, w5), w6);
        *(float4*)(&shm[r * P + 4 * q]) = h;
    }
    __syncthreads();

    // ---- Phase B: vertical min3 -> sm; -inf at invalid (OOB-center) cells ----
    for (int item = t; item < 66 * 17; item += 256) {
        int rm = item / 17, q = item - rm * 17;
        const float* p0 = &shm[rm * P + 4 * q];
        float4 a = *(const float4*)p0;
        float4 b = *(const float4*)(p0 + P);
        float4 c = *(const float4*)(p0 + 2 * P);
        int y = by + rm - 1;
        bool yv = (unsigned)y < (unsigned)IMG_H;
        int xb = bx + 4 * q - 2;
        float4 v;
        v.x = (yv && (unsigned)(xb + 0) < (unsigned)IMG_W) ? fminf(fminf(a.x, b.x), c.x) : -INF;
        v.y = (yv && (unsigned)(xb + 1) < (unsigned)IMG_W) ? fminf(fminf(a.y, b.y), c.y) : -INF;
        v.z = (yv && (unsigned)(xb + 2) < (unsigned)IMG_W) ? fminf(fminf(a.z, b.z), c.z) : -INF;
        v.w = (yv && (unsigned)(xb + 3) < (unsigned)IMG_W) ? fminf(fminf(a.w, b.w), c.w) : -INF;
        *(float4*)(&sm[rm * P + 4 * q]) = v;
    }
    __syncthreads();

    // ---- Phase C: horizontal max3 of m -> shm (col c2 in [0,63], 66 rows) ----
    // hM[c2] = max(m[s=c2+1..c2+3])
    for (int item = t; item < 66 * 16; item += 256) {
        int r2 = item >> 4, q = item & 15;
        const float* p0 = &sm[r2 * P + 4 * q];
        float4 A = *(const float4*)p0;
        float4 B = *(const float4*)(p0 + 4);
        float w1 = A.y, w2 = A.z, w3 = A.w, w4 = B.x, w5 = B.y, w6 = B.z;
        float4 h;
        h.x = fmaxf(fmaxf(w1, w2), w3);
        h.y = fmaxf(fmaxf(w2, w3), w4);
        h.z = fmaxf(fmaxf(w3, w4), w5);
        h.w = fmaxf(fmaxf(w4, w5), w6);
        *(float4*)(&shm[r2 * P + 4 * q]) = h;
    }
    __syncthreads();

    // ---- Phase D: vertical max3 + contour + relu update + store ----
    for (int item = t; item < 64 * 16; item += 256) {
        int ry = item >> 4, q = item & 15;
        const float* pM = &shm[ry * P + 4 * q];
        float4 a = *(const float4*)pM;
        float4 b = *(const float4*)(pM + P);
        float4 c = *(const float4*)(pM + 2 * P);
        float4 M;
        M.x = fmaxf(fmaxf(a.x, b.x), c.x);
        M.y = fmaxf(fmaxf(a.y, b.y), c.y);
        M.z = fmaxf(fmaxf(a.z, b.z), c.z);
        M.w = fmaxf(fmaxf(a.w, b.w), c.w);
        const float* pm = &sm[(ry + 1) * P + 4 * q];
        float4 mA = *(const float4*)pm;        // s = 4q..4q+3
        float4 mB = *(const float4*)(pm + 4);  // s = 4q+4..4q+7
        // minc_i = m[s = 4q+2+i] -> {mA.z, mA.w, mB.x, mB.y}
        int y = by + ry;
        const float* gx = s + (size_t)y * IMG_W + bx + 4 * q;
        float4 xv = *(const float4*)gx;
        float4 out;
        out.x = fmaxf(xv.x - fmaxf(M.x - mA.z, 0.f), 0.f);
        out.y = fmaxf(xv.y - fmaxf(M.y - mA.w, 0.f), 0.f);
        out.z = fmaxf(xv.z - fmaxf(M.z - mB.x, 0.f), 0.f);
        out.w = fmaxf(xv.w - fmaxf(M.w - mB.y, 0.f), 0.f);
        *(float4*)(o + (size_t)y * IMG_W + bx + 4 * q) = out;
    }
}

// acc2[0] += sum(skel * other); acc2[1] += sum(skel)   (float4, full grid)
__global__ __launch_bounds__(256) void reduce2(
    const float* __restrict__ skel,
    const float* __restrict__ other,
    double* __restrict__ acc2)
{
    const size_t N4 = (size_t)NIMG * IMG_N / 4;   // 4,194,304
    size_t i = (size_t)blockIdx.x * 256 + threadIdx.x;
    const size_t stride = (size_t)gridDim.x * 256;
    float s1 = 0.f, s2 = 0.f;
    for (; i < N4; i += stride) {
        float4 sk = ((const float4*)skel)[i];
        float4 ot = ((const float4*)other)[i];
        s1 += sk.x * ot.x + sk.y * ot.y + sk.z * ot.z + sk.w * ot.w;
        s2 += sk.x + sk.y + sk.z + sk.w;
    }
    double d1 = s1, d2 = s2;
    for (int off = 32; off; off >>= 1) {
        d1 += __shfl_down(d1, off);
        d2 += __shfl_down(d2, off);
    }
    if ((threadIdx.x & 63) == 0) {
        atomicAdd(&acc2[0], d1);
        atomicAdd(&acc2[1], d2);
    }
}

__global__ void zero_acc(double* __restrict__ acc)
{
    if (threadIdx.x < 4) acc[threadIdx.x] = 0.0;
}

__global__ void finalize(const double* __restrict__ acc, float* __restrict__ out)
{
    double iflat = (acc[0] + 1.0) / (acc[1] + 1.0);
    double tflat = (acc[2] + 1.0) / (acc[3] + 1.0);
    double inter = iflat * tflat;
    out[0] = (float)(1.0 - 2.0 * inter / (iflat + tflat));
}

extern "C" void kernel_launch(void* const* d_in, const int* in_sizes, int n_in,
                              void* d_out, int out_size, void* d_ws, size_t ws_size,
                              hipStream_t stream)
{
    const float* pred = (const float*)d_in[0];
    const float* gt   = (const float*)d_in[1];

    double* acc  = (double*)d_ws;                   // 4 doubles @ +0
    float*  bufA = (float*)((char*)d_ws + 256);     // 16 images
    float*  bufB = bufA + (size_t)NIMG * IMG_N;     // 16 images

    zero_acc<<<1, 64, 0, stream>>>(acc);

    dim3 grid(IMG_W / TS, IMG_H / TS, NIMG);

    // ---- skeletonize pred ----
    skel_iter<<<grid, 256, 0, stream>>>(pred, bufA);
    for (int i = 1; i < ITERS; ++i) {
        const float* sp = (i & 1) ? bufA : bufB;
        float*       dp = (i & 1) ? bufB : bufA;
        skel_iter<<<grid, 256, 0, stream>>>(sp, dp);
    }
    reduce2<<<4096, 256, 0, stream>>>(bufB, gt, acc);        // iflat sums

    // ---- skeletonize gt ----
    skel_iter<<<grid, 256, 0, stream>>>(gt, bufA);
    for (int i = 1; i < ITERS; ++i) {
        const float* sp = (i & 1) ? bufA : bufB;
        float*       dp = (i & 1) ? bufB : bufA;
        skel_iter<<<grid, 256, 0, stream>>>(sp, dp);
    }
    reduce2<<<4096, 256, 0, stream>>>(bufB, pred, acc + 2);  // tflat sums

    finalize<<<1, 1, 0, stream>>>(acc, (float*)d_out);
}

// Round 4
// 1199.248 us; speedup vs baseline: 2.1167x; 2.0447x over previous
//
#include <hip/hip_runtime.h>
#include <math.h>

// clDice loss on MI355X (gfx950).
// soft_skeletonize = 20 iterations of:
//   m = minpool3(x); contour = relu(maxpool3(m) - m); x = relu(x - contour)
// Round-4: row-streaming separable kernel. One block = full 1024-px image row
// (256 threads x float4); streams a 16-row output band top-to-bottom holding
// the separable pipeline (hmin -> vmin -> hmax -> vmax -> update) in register
// rolling windows. LDS is only two double-buffered row buffers (x-row, m-row)
// for the +-1 column neighbor exchange => ~24 B LDS traffic per output px
// (round-3 tiled: ~54 B/px) and 2 barriers/row. Round-3 reduce2 was atomic-
// bound (32k serialized f64 atomics = 404 us); now 2 atomics per block.

#define IMG_H 1024
#define IMG_W 1024
#define IMG_N (IMG_H * IMG_W)
#define NIMG  16
#define BH    16              // output rows per block
#define NB    (IMG_H / BH)    // 64 bands
#define ITERS 20
#define BUFW  1032            // 4 guard + 1024 + 4 guard floats

__device__ __forceinline__ float min3f(float a, float b, float c) { return fminf(fminf(a, b), c); }
__device__ __forceinline__ float max3f(float a, float b, float c) { return fmaxf(fmaxf(a, b), c); }

__global__ __launch_bounds__(256) void skel_stream(
    const float* __restrict__ src,
    float* __restrict__ dst)
{
    __shared__ __align__(16) float xb[2][BUFW];   // x rows, guards = +inf
    __shared__ __align__(16) float mb[2][BUFW];   // m rows, guards = -inf

    const int t = threadIdx.x;
    const int c = 4 * t;                          // column base
    const int r0 = blockIdx.x * BH;
    const float* s = src + (size_t)blockIdx.y * IMG_N;
    float*       o = dst + (size_t)blockIdx.y * IMG_N;
    const float INF = __builtin_huge_valf();

    if (t < 4) {
        xb[0][t] = INF;  xb[1][t] = INF;  xb[0][1028 + t] = INF;  xb[1][1028 + t] = INF;
        mb[0][t] = -INF; mb[1][t] = -INF; mb[0][1028 + t] = -INF; mb[1][1028 + t] = -INF;
    }

    // register rolling windows (float4 = 4 columns each)
    float4 hm1, hm2;          // hmin rows y-2, y-1
    float4 m_y2, m_y3;        // m rows y-2, y-3
    float4 q1, q2;            // hmax(m) rows y-4, y-3
    float4 x1, x2, x3;        // x rows y-1, y-2, y-3
    hm1 = hm2 = make_float4(INF, INF, INF, INF);
    m_y2 = m_y3 = make_float4(-INF, -INF, -INF, -INF);
    q1 = q2 = make_float4(-INF, -INF, -INF, -INF);
    x1 = x2 = x3 = make_float4(INF, INF, INF, INF);

    const int y0 = r0 - 2;
    float4 xcur = ((unsigned)y0 < (unsigned)IMG_H)
                      ? *(const float4*)(s + (size_t)y0 * IMG_W + c)
                      : make_float4(INF, INF, INF, INF);

    for (int y = y0; y <= r0 + BH + 2; ++y) {
        // prefetch next x row (consumed at end of this step)
        const int yn = y + 1;
        float4 xnext = make_float4(INF, INF, INF, INF);
        if ((unsigned)yn < (unsigned)IMG_H)
            xnext = *(const float4*)(s + (size_t)yn * IMG_W + c);

        const int buf = y & 1;
        __syncthreads();                           // prior readers of xb/mb[buf] done
        *(float4*)&xb[buf][4 + c] = xcur;
        __syncthreads();                           // xb[buf] visible

        // ---- h-min3 of x row y ----
        float nL = xb[buf][3 + c];
        float nR = xb[buf][8 + c];
        float4 h;
        h.x = min3f(nL,     xcur.x, xcur.y);
        h.y = min3f(xcur.x, xcur.y, xcur.z);
        h.z = min3f(xcur.y, xcur.z, xcur.w);
        h.w = min3f(xcur.z, xcur.w, nR);

        // ---- v-min3 -> m row (y-1); OOB row => -inf (maxpool pad) ----
        const bool mvalid = (unsigned)(y - 1) < (unsigned)IMG_H;
        float4 mA;
        mA.x = mvalid ? min3f(hm1.x, hm2.x, h.x) : -INF;
        mA.y = mvalid ? min3f(hm1.y, hm2.y, h.y) : -INF;
        mA.z = mvalid ? min3f(hm1.z, hm2.z, h.z) : -INF;
        mA.w = mvalid ? min3f(hm1.w, hm2.w, h.w) : -INF;
        *(float4*)&mb[buf][4 + c] = mA;            // consumed next step

        // ---- h-max3 of m row (y-2): regs m_y2 + LDS neighbors from prev step ----
        float mL = mb[buf ^ 1][3 + c];
        float mR = mb[buf ^ 1][8 + c];
        float4 q;
        q.x = max3f(mL,     m_y2.x, m_y2.y);
        q.y = max3f(m_y2.x, m_y2.y, m_y2.z);
        q.z = max3f(m_y2.y, m_y2.z, m_y2.w);
        q.w = max3f(m_y2.z, m_y2.w, mR);

        // ---- v-max3 -> M row (y-3); contour; update; store ----
        if (y >= r0 + 3) {
            float4 M;
            M.x = max3f(q1.x, q2.x, q.x);
            M.y = max3f(q1.y, q2.y, q.y);
            M.z = max3f(q1.z, q2.z, q.z);
            M.w = max3f(q1.w, q2.w, q.w);
            float4 outv;
            outv.x = fmaxf(x3.x - fmaxf(M.x - m_y3.x, 0.f), 0.f);
            outv.y = fmaxf(x3.y - fmaxf(M.y - m_y3.y, 0.f), 0.f);
            outv.z = fmaxf(x3.z - fmaxf(M.z - m_y3.z, 0.f), 0.f);
            outv.w = fmaxf(x3.w - fmaxf(M.w - m_y3.w, 0.f), 0.f);
            *(float4*)(o + (size_t)(y - 3) * IMG_W + c) = outv;
        }

        // ---- ring shifts ----
        hm1 = hm2;  hm2 = h;
        m_y3 = m_y2; m_y2 = mA;
        q1 = q2;    q2 = q;
        x3 = x2;    x2 = x1;  x1 = xcur;
        xcur = xnext;
    }
}

// acc2[0] += sum(skel * other); acc2[1] += sum(skel). 2 atomics per BLOCK.
__global__ __launch_bounds__(256) void reduce2(
    const float* __restrict__ skel,
    const float* __restrict__ other,
    double* __restrict__ acc2)
{
    __shared__ double l1[4], l2[4];
    const size_t N4 = (size_t)NIMG * IMG_N / 4;
    size_t i = (size_t)blockIdx.x * 256 + threadIdx.x;
    const size_t stride = (size_t)gridDim.x * 256;
    float s1 = 0.f, s2 = 0.f;
    for (; i < N4; i += stride) {
        float4 sk = ((const float4*)skel)[i];
        float4 ot = ((const float4*)other)[i];
        s1 += sk.x * ot.x + sk.y * ot.y + sk.z * ot.z + sk.w * ot.w;
        s2 += sk.x + sk.y + sk.z + sk.w;
    }
    double d1 = s1, d2 = s2;
    for (int off = 32; off; off >>= 1) {
        d1 += __shfl_down(d1, off);
        d2 += __shfl_down(d2, off);
    }
    const int w = threadIdx.x >> 6;
    if ((threadIdx.x & 63) == 0) { l1[w] = d1; l2[w] = d2; }
    __syncthreads();
    if (threadIdx.x == 0) {
        atomicAdd(&acc2[0], l1[0] + l1[1] + l1[2] + l1[3]);
        atomicAdd(&acc2[1], l2[0] + l2[1] + l2[2] + l2[3]);
    }
}

__global__ void zero_acc(double* __restrict__ acc)
{
    if (threadIdx.x < 4) acc[threadIdx.x] = 0.0;
}

__global__ void finalize(const double* __restrict__ acc, float* __restrict__ out)
{
    double iflat = (acc[0] + 1.0) / (acc[1] + 1.0);
    double tflat = (acc[2] + 1.0) / (acc[3] + 1.0);
    double inter = iflat * tflat;
    out[0] = (float)(1.0 - 2.0 * inter / (iflat + tflat));
}

extern "C" void kernel_launch(void* const* d_in, const int* in_sizes, int n_in,
                              void* d_out, int out_size, void* d_ws, size_t ws_size,
                              hipStream_t stream)
{
    const float* pred = (const float*)d_in[0];
    const float* gt   = (const float*)d_in[1];

    double* acc  = (double*)d_ws;                   // 4 doubles @ +0
    float*  bufA = (float*)((char*)d_ws + 256);     // 16 images
    float*  bufB = bufA + (size_t)NIMG * IMG_N;     // 16 images

    zero_acc<<<1, 64, 0, stream>>>(acc);

    dim3 grid(NB, NIMG);                            // 64 bands x 16 images

    // ---- skeletonize pred ----
    skel_stream<<<grid, 256, 0, stream>>>(pred, bufA);
    for (int i = 1; i < ITERS; ++i) {
        const float* sp = (i & 1) ? bufA : bufB;
        float*       dp = (i & 1) ? bufB : bufA;
        skel_stream<<<grid, 256, 0, stream>>>(sp, dp);
    }
    reduce2<<<1024, 256, 0, stream>>>(bufB, gt, acc);        // iflat sums

    // ---- skeletonize gt ----
    skel_stream<<<grid, 256, 0, stream>>>(gt, bufA);
    for (int i = 1; i < ITERS; ++i) {
        const float* sp = (i & 1) ? bufA : bufB;
        float*       dp = (i & 1) ? bufB : bufA;
        skel_stream<<<grid, 256, 0, stream>>>(sp, dp);
    }
    reduce2<<<1024, 256, 0, stream>>>(bufB, pred, acc + 2);  // tflat sums

    finalize<<<1, 1, 0, stream>>>(acc, (float*)d_out);
}

// Round 5
// 820.180 us; speedup vs baseline: 3.0949x; 1.4622x over previous
//
#include <hip/hip_runtime.h>
#include <math.h>

// clDice loss on MI355X (gfx950).
// soft_skeletonize = 20 iterations of:
//   m = minpool3(x); contour = relu(maxpool3(m) - m); x = relu(x - contour)
// Round-5: temporal fusion. K=4 skeleton iterations fused per launch as a
// 4-stage software pipeline of the round-4 row-streaming stage. Round-4 was
// AT the memory roofline (155 MB/launch @ 5.7 TB/s eff = 27 us measured), so
// the win is traffic: 10 launches x ~170 MB instead of 40 x 155 MB.
// Each stage: separable hmin -> vmin -> hmax -> vmax in register rolling
// windows; per-stage double-buffered LDS rows give the +-1 column exchange
// with only 2 barriers per iteration for ALL stages (write buf, read buf^1).
// Stage s lags stage s-1 by 4 rows; emits chain via registers.
// Final reduction (sum(skel*other), sum(skel)) fused into the last launch.

#define IMG_H 1024
#define IMG_W 1024
#define IMG_N (IMG_H * IMG_W)
#define NIMG  16
#define BH    32              // output rows per band
#define NBANDS (IMG_H / BH)   // 32
#define K     4               // fused skeleton iterations per launch
#define BUFW  1032            // 4 guard + 1024 + 4 guard floats
#define ITER_PAIRS ((BH + 24) / 2)   // 56 iterations (55 needed + 1 harmless)

__device__ __forceinline__ float min3f(float a, float b, float c) { return fminf(fminf(a, b), c); }
__device__ __forceinline__ float max3f(float a, float b, float c) { return fmaxf(fmaxf(a, b), c); }
__device__ __forceinline__ float4 f4(float v) { return make_float4(v, v, v, v); }

__device__ __forceinline__ float4 ldrow(const float* base, int y, int c)
{
    if ((unsigned)y < (unsigned)IMG_H)
        return *(const float4*)(base + (size_t)y * IMG_W + c);
    return f4(__builtin_huge_valf());
}

struct St {
    float4 hm1, hm2;    // hmin rows ri-2, ri-1
    float4 m2, m3;      // minpool rows ri-2, ri-3
    float4 q1, q2;      // hmax rows ri-4, ri-3
    float4 x1, x2, x3;  // input rows ri-1, ri-2, ri-3
    float4 xc;          // input row ri
};

// One pipeline stage at input row ri. Emits output row ri-3.
template<int BUF>
__device__ __forceinline__ float4 stage_step(
    St& s, int ri, int c, float (&xsh)[2][BUFW], float (&msh)[2][BUFW])
{
    const float INF = __builtin_huge_valf();
    // h-min3 of input row ri (neighbors via LDS, center in register)
    float nL = xsh[BUF][3 + c];
    float nR = xsh[BUF][8 + c];
    float4 h;
    h.x = min3f(nL,     s.xc.x, s.xc.y);
    h.y = min3f(s.xc.x, s.xc.y, s.xc.z);
    h.z = min3f(s.xc.y, s.xc.z, s.xc.w);
    h.w = min3f(s.xc.z, s.xc.w, nR);
    // v-min3 -> m row ri-1 (-inf when row outside image: maxpool padding)
    float4 m;
    if ((unsigned)(ri - 1) < (unsigned)IMG_H) {
        m.x = min3f(s.hm1.x, s.hm2.x, h.x);
        m.y = min3f(s.hm1.y, s.hm2.y, h.y);
        m.z = min3f(s.hm1.z, s.hm2.z, h.z);
        m.w = min3f(s.hm1.w, s.hm2.w, h.w);
    } else {
        m = f4(-INF);
    }
    *(float4*)&msh[BUF][4 + c] = m;          // consumed (neighbors) next iter
    // h-max3 of m row ri-2 (center in reg m2, neighbors from prev-iter LDS)
    float mL = msh[BUF ^ 1][3 + c];
    float mR = msh[BUF ^ 1][8 + c];
    float4 q;
    q.x = max3f(mL,     s.m2.x, s.m2.y);
    q.y = max3f(s.m2.x, s.m2.y, s.m2.z);
    q.z = max3f(s.m2.y, s.m2.z, s.m2.w);
    q.w = max3f(s.m2.z, s.m2.w, mR);
    // v-max3 -> M row ri-3; contour = relu(M - m); out = relu(x - contour)
    float4 M;
    M.x = max3f(s.q1.x, s.q2.x, q.x);
    M.y = max3f(s.q1.y, s.q2.y, q.y);
    M.z = max3f(s.q1.z, s.q2.z, q.z);
    M.w = max3f(s.q1.w, s.q2.w, q.w);
    float4 e;
    e.x = fmaxf(s.x3.x - fmaxf(M.x - s.m3.x, 0.f), 0.f);
    e.y = fmaxf(s.x3.y - fmaxf(M.y - s.m3.y, 0.f), 0.f);
    e.z = fmaxf(s.x3.z - fmaxf(M.z - s.m3.z, 0.f), 0.f);
    e.w = fmaxf(s.x3.w - fmaxf(M.w - s.m3.w, 0.f), 0.f);
    // ring shifts
    s.hm1 = s.hm2; s.hm2 = h;
    s.m3  = s.m2;  s.m2  = m;
    s.q1  = s.q2;  s.q2  = q;
    s.x3  = s.x2;  s.x2  = s.x1; s.x1 = s.xc;
    return e;
}

template<int BUF>
__device__ __forceinline__ void iter_step(
    int y, int c, int r0, St (&st)[K],
    const float* __restrict__ s, float* __restrict__ o,
    const float* __restrict__ other, float& a1, float& a2,
    float (&xsh)[K][2][BUFW], float (&msh)[K][2][BUFW])
{
    const float INF = __builtin_huge_valf();
    float4 xnext = ldrow(s, y + 1, c);       // prefetch stage-0 input
    __syncthreads();                         // prior readers of buf done
    #pragma unroll
    for (int k = 0; k < K; ++k)
        *(float4*)&xsh[k][BUF][4 + c] = st[k].xc;
    __syncthreads();                         // xsh[.][BUF] visible
    float4 em[K];
    #pragma unroll
    for (int k = 0; k < K; ++k)
        em[k] = stage_step<BUF>(st[k], y - 4 * k, c, xsh[k], msh[k]);
    // chain emits to next stage's input (force +inf for out-of-image rows)
    #pragma unroll
    for (int k = K - 1; k >= 1; --k) {
        int er = y - 4 * (k - 1) - 3;        // row emitted by stage k-1
        if ((unsigned)er < (unsigned)IMG_H) st[k].xc = em[k - 1];
        else                                 st[k].xc = f4(INF);
    }
    st[0].xc = xnext;
    // final-stage store (+ optional fused reduction)
    int orow = y - (4 * (K - 1) + 3);        // y - 15
    if ((unsigned)(orow - r0) < (unsigned)BH) {
        float4 e = em[K - 1];
        *(float4*)(o + (size_t)orow * IMG_W + c) = e;
        if (other) {
            float4 ov = *(const float4*)(other + (size_t)orow * IMG_W + c);
            a1 += e.x * ov.x + e.y * ov.y + e.z * ov.z + e.w * ov.w;
            a2 += e.x + e.y + e.z + e.w;
        }
    }
}

__global__ __launch_bounds__(256, 2) void skel4(
    const float* __restrict__ src, float* __restrict__ dst,
    const float* __restrict__ other, double* __restrict__ acc2)
{
    __shared__ __align__(16) float xsh[K][2][BUFW];   // guards = +inf
    __shared__ __align__(16) float msh[K][2][BUFW];   // guards = -inf
    __shared__ double l1[4], l2[4];

    const int t = threadIdx.x, c = 4 * t;
    const int r0 = blockIdx.x * BH;
    const float* s = src + (size_t)blockIdx.y * IMG_N;
    float*       o = dst + (size_t)blockIdx.y * IMG_N;
    const float INF = __builtin_huge_valf();

    if (t < 4) {
        #pragma unroll
        for (int k = 0; k < K; ++k) {
            #pragma unroll
            for (int b = 0; b < 2; ++b) {
                xsh[k][b][t] = INF;  xsh[k][b][1028 + t] = INF;
                msh[k][b][t] = -INF; msh[k][b][1028 + t] = -INF;
            }
        }
    }

    St st[K];
    #pragma unroll
    for (int k = 0; k < K; ++k) {
        st[k].hm1 = st[k].hm2 = f4(INF);
        st[k].m2 = st[k].m3 = f4(-INF);
        st[k].q1 = st[k].q2 = f4(-INF);
        st[k].x1 = st[k].x2 = st[k].x3 = f4(INF);
        st[k].xc = f4(INF);
    }
    st[0].xc = ldrow(s, r0 - 8, c);          // first stage-0 input row

    float a1 = 0.f, a2 = 0.f;
    const int y0 = r0 - 8;                   // even -> BUF parity compile-time
    for (int p = 0; p < ITER_PAIRS; ++p) {
        int y = y0 + 2 * p;
        iter_step<0>(y,     c, r0, st, s, o, other, a1, a2, xsh, msh);
        iter_step<1>(y + 1, c, r0, st, s, o, other, a1, a2, xsh, msh);
    }

    if (other) {                             // fused reduction epilogue
        double d1 = a1, d2 = a2;
        for (int off = 32; off; off >>= 1) {
            d1 += __shfl_down(d1, off);
            d2 += __shfl_down(d2, off);
        }
        const int w = t >> 6;
        if ((t & 63) == 0) { l1[w] = d1; l2[w] = d2; }
        __syncthreads();
        if (t == 0) {
            atomicAdd(&acc2[0], l1[0] + l1[1] + l1[2] + l1[3]);
            atomicAdd(&acc2[1], l2[0] + l2[1] + l2[2] + l2[3]);
        }
    }
}

__global__ void zero_acc(double* __restrict__ acc)
{
    if (threadIdx.x < 4) acc[threadIdx.x] = 0.0;
}

__global__ void finalize(const double* __restrict__ acc, float* __restrict__ out)
{
    double iflat = (acc[0] + 1.0) / (acc[1] + 1.0);
    double tflat = (acc[2] + 1.0) / (acc[3] + 1.0);
    double inter = iflat * tflat;
    out[0] = (float)(1.0 - 2.0 * inter / (iflat + tflat));
}

extern "C" void kernel_launch(void* const* d_in, const int* in_sizes, int n_in,
                              void* d_out, int out_size, void* d_ws, size_t ws_size,
                              hipStream_t stream)
{
    const float* pred = (const float*)d_in[0];
    const float* gt   = (const float*)d_in[1];

    double* acc  = (double*)d_ws;                   // 4 doubles @ +0
    float*  bufA = (float*)((char*)d_ws + 256);     // 16 images
    float*  bufB = bufA + (size_t)NIMG * IMG_N;     // 16 images

    zero_acc<<<1, 64, 0, stream>>>(acc);

    dim3 grid(NBANDS, NIMG);                        // 32 bands x 16 images

    // ---- pred skeleton: 5 launches x 4 fused iterations = 20 ----
    skel4<<<grid, 256, 0, stream>>>(pred, bufA, nullptr, nullptr);
    skel4<<<grid, 256, 0, stream>>>(bufA, bufB, nullptr, nullptr);
    skel4<<<grid, 256, 0, stream>>>(bufB, bufA, nullptr, nullptr);
    skel4<<<grid, 256, 0, stream>>>(bufA, bufB, nullptr, nullptr);
    skel4<<<grid, 256, 0, stream>>>(bufB, bufA, gt, acc);        // + iflat sums

    // ---- gt skeleton ----
    skel4<<<grid, 256, 0, stream>>>(gt,   bufB, nullptr, nullptr);
    skel4<<<grid, 256, 0, stream>>>(bufB, bufA, nullptr, nullptr);
    skel4<<<grid, 256, 0, stream>>>(bufA, bufB, nullptr, nullptr);
    skel4<<<grid, 256, 0, stream>>>(bufB, bufA, nullptr, nullptr);
    skel4<<<grid, 256, 0, stream>>>(bufA, bufB, pred, acc + 2);  // + tflat sums

    finalize<<<1, 1, 0, stream>>>(acc, (float*)d_out);
}